// Round 12
// baseline (195.052 us; speedup 1.0000x reference)
//
#include <hip/hip_runtime.h>
#include <math.h>

#define DIMH 256        // D
#define NB   32         // batch
#define E_TOT 43234
#define EPB  32         // entities per block -> 1352 blocks (5.3/CU vs 3-block cap: backfill queue)
// reference: phase = rel / (REL_RANGE/PI); REL_RANGE/PI = 0.03125/PI
#define PHASE_DIV 0.009947183943243459f

typedef float v2f __attribute__((ext_vector_type(2)));
typedef float v4f __attribute__((ext_vector_type(4)));

// Kernel 1: rotate head by relation phase; interleaved layout per (b, dpair):
// rot_v4[b*128+dp] = (re_2dp, re_2dp+1, im_2dp, im_2dp+1).
__global__ __launch_bounds__(256) void rot_kernel(const float* __restrict__ head,
                                                  const float* __restrict__ rel,
                                                  float4* __restrict__ rot_v4) {
    int i  = blockIdx.x * 256 + threadIdx.x;   // 0..4095
    int b  = i >> 7;
    int dp = i & 127;
    int d0 = dp * 2;
    float4 w;
    {
        float re_h = head[b * 2 * DIMH + d0];
        float im_h = head[b * 2 * DIMH + DIMH + d0];
        float s, c;
        sincosf(rel[b * DIMH + d0] / PHASE_DIV, &s, &c);
        w.x = re_h * c - im_h * s;
        w.z = re_h * s + im_h * c;
    }
    {
        float re_h = head[b * 2 * DIMH + d0 + 1];
        float im_h = head[b * 2 * DIMH + DIMH + d0 + 1];
        float s, c;
        sincosf(rel[b * DIMH + d0 + 1] / PHASE_DIV, &s, &c);
        w.y = re_h * c - im_h * s;
        w.w = re_h * s + im_h * c;
    }
    rot_v4[b * (DIMH / 2) + dp] = w;
}

__device__ __forceinline__ v2f sqrt2(v2f s) {
    v2f r;
    r.x = __builtin_amdgcn_sqrtf(s.x);   // quarter-rate trans; issue-serial with VALU (R8/R9 fit)
    r.y = __builtin_amdgcn_sqrtf(s.y);
    return r;
}

// Sum over each 32-lane half of the wave, on the VALU pipe (DPP). Result in
// lanes 31 and 63. Verified correct in R11 (absmax 2.0 = bf16-ref floor).
__device__ __forceinline__ float dpp_reduce32(float h) {
    h += __int_as_float(__builtin_amdgcn_update_dpp(0, __float_as_int(h), 0x111, 0xf, 0xf, true)); // shr1
    h += __int_as_float(__builtin_amdgcn_update_dpp(0, __float_as_int(h), 0x112, 0xf, 0xf, true)); // shr2
    h += __int_as_float(__builtin_amdgcn_update_dpp(0, __float_as_int(h), 0x114, 0xf, 0xf, true)); // shr4
    h += __int_as_float(__builtin_amdgcn_update_dpp(0, __float_as_int(h), 0x118, 0xf, 0xf, true)); // shr8
    h += __int_as_float(__builtin_amdgcn_update_dpp(0, __float_as_int(h), 0x142, 0xf, 0xf, true)); // bcast15
    return h;
}

// Kernel 2 (BARRIER-FREE): thread = (batch-group bg 0..7) x (d-slice ds 0..31).
// rot lives in registers (64 VGPR, loaded once). Entities stream straight
// from global into registers — NO LDS, NO __syncthreads. R8/R9 busy-cycle
// fit showed issue floor ~40 us and the 46% idle came from the barriered
// staging structure; pure streaming removes it. The 4 waves of a block read
// the same entity rows (L1-dedup; ent is LLC-resident — FETCH has been
// 43 MB < 88 MB ent size every round). 1-entity register prefetch.
__global__ __launch_bounds__(256, 3) void dist_kernel(const float* __restrict__ ent,
                                                      const float4* __restrict__ rot_v4,
                                                      float* __restrict__ out) {
    const int tid = threadIdx.x;
    const int ds  = tid & 31;          // d-slice: d in [8*ds, 8*ds+8)
    const int bg  = tid >> 5;          // batch group: b = 4*bg + jj
    const int eb  = blockIdx.x * EPB;

    // ---- rot -> registers (16 x b128 per thread, once per block)
    v2f rr[4][4], ri[4][4];
    #pragma unroll
    for (int jj = 0; jj < 4; ++jj) {
        const int b = bg * 4 + jj;
        #pragma unroll
        for (int p = 0; p < 4; ++p) {
            float4 w = rot_v4[b * (DIMH / 2) + ds * 4 + p];
            rr[jj][p].x = w.x; rr[jj][p].y = w.y;
            ri[jj][p].x = w.z; ri[jj][p].y = w.w;
        }
    }

    // entity slice loads: 4 x b128 per entity; lanes 0..31 stride 32 B ->
    // coalesced 1 KB segments; lanes 32..63 duplicate (HW merges).
    v4f cur[4], nxt[4];
    auto load_e = [&](int e, v4f* buf) {
        e = min(e, E_TOT - 1);                 // clamp tail; stores guarded
        const float* b = &ent[(size_t)e * (2 * DIMH) + ds * 8];
        buf[0] = *reinterpret_cast<const v4f*>(b);              // re d 0..3
        buf[1] = *reinterpret_cast<const v4f*>(b + 4);          // re d 4..7
        buf[2] = *reinterpret_cast<const v4f*>(b + DIMH);       // im d 0..3
        buf[3] = *reinterpret_cast<const v4f*>(b + DIMH + 4);   // im d 4..7
    };

    load_e(eb, cur);

    for (int i = 0; i < EPB; ++i) {
        if (i + 1 < EPB) load_e(eb + i + 1, nxt);

        v2f er[4], ei[4];
        er[0] = cur[0].xy; er[1] = cur[0].zw; er[2] = cur[1].xy; er[3] = cur[1].zw;
        ei[0] = cur[2].xy; ei[1] = cur[2].zw; ei[2] = cur[3].xy; ei[3] = cur[3].zw;

        v2f acc[4];
        #pragma unroll
        for (int jj = 0; jj < 4; ++jj) { acc[jj].x = 0.f; acc[jj].y = 0.f; }

        #pragma unroll
        for (int p = 0; p < 4; ++p)
            #pragma unroll
            for (int jj = 0; jj < 4; ++jj) {
                v2f a = rr[jj][p] - er[p];
                v2f b = ri[jj][p] - ei[p];
                acc[jj] += sqrt2(a * a + b * b);   // pk_mul+pk_fma then 2x v_sqrt
            }

        const int e = eb + i;
        #pragma unroll
        for (int jj = 0; jj < 4; ++jj) {
            float h = dpp_reduce32(acc[jj].x + acc[jj].y);
            if ((tid & 31) == 31 && e < E_TOT)
                out[(size_t)(bg * 4 + jj) * E_TOT + e] = 6.0f - h;
        }

        #pragma unroll
        for (int q = 0; q < 4; ++q) cur[q] = nxt[q];
    }
}

extern "C" void kernel_launch(void* const* d_in, const int* in_sizes, int n_in,
                              void* d_out, int out_size, void* d_ws, size_t ws_size,
                              hipStream_t stream) {
    const float* head = (const float*)d_in[0];   // (32, 512)
    const float* rel  = (const float*)d_in[1];   // (32, 256)
    const float* ent  = (const float*)d_in[2];   // (43234, 512)
    float4* rot_v4 = (float4*)d_ws;              // 32 * 128 * 16 B = 64 KB

    rot_kernel<<<(NB * DIMH / 2) / 256, 256, 0, stream>>>(head, rel, rot_v4);

    int eblocks = (E_TOT + EPB - 1) / EPB;       // 1352
    dist_kernel<<<eblocks, 256, 0, stream>>>(ent, rot_v4, (float*)d_out);
}

// Round 13
// 192.157 us; speedup vs baseline: 1.0151x; 1.0151x over previous
//
#include <hip/hip_runtime.h>
#include <math.h>

#define DIMH 256        // D
#define NB   32         // batch
#define E_TOT 43234
#define TE   32         // entities per block  (1352 blocks = 5.28/CU)
#define DK   32         // d-chunk staged in LDS
#define NC   (DIMH / DK)  // 8 chunks
// reference: phase = rel / (REL_RANGE/PI); REL_RANGE/PI = 0.03125/PI
#define PHASE_DIV 0.009947183943243459f

typedef float v2f __attribute__((ext_vector_type(2)));
typedef float v4f __attribute__((ext_vector_type(4)));

// Kernel 1: rotate head by relation phase; emit rot directly in the
// interleaved v4f layout (re_2p, re_2p+1, im_2p, im_2p+1) per (b, dpair).
__global__ __launch_bounds__(256) void rot_kernel(const float* __restrict__ head,
                                                  const float* __restrict__ rel,
                                                  float4* __restrict__ rot_v4) {
    int i  = blockIdx.x * 256 + threadIdx.x;   // 0..4095
    int b  = i >> 7;
    int dp = i & 127;
    int d0 = dp * 2;
    float4 w;
    {
        float re_h = head[b * 2 * DIMH + d0];
        float im_h = head[b * 2 * DIMH + DIMH + d0];
        float s, c;
        sincosf(rel[b * DIMH + d0] / PHASE_DIV, &s, &c);
        w.x = re_h * c - im_h * s;
        w.z = re_h * s + im_h * c;
    }
    {
        float re_h = head[b * 2 * DIMH + d0 + 1];
        float im_h = head[b * 2 * DIMH + DIMH + d0 + 1];
        float s, c;
        sincosf(rel[b * DIMH + d0 + 1] / PHASE_DIV, &s, &c);
        w.y = re_h * c - im_h * s;
        w.w = re_h * s + im_h * c;
    }
    rot_v4[b * (DIMH / 2) + dp] = w;
}

// HYBRID sqrt: the 12-round invariant ~78us wall is the v_sqrt_f32 pipe
// (~30 SIMD-cyc per wave-instr; 3.54e8 lane-sqrts = ~72us device-wide).
// Full v_sqrt (R8) = trans-bound 78us; full NR (R9) = VALU-bound ~95us.
// Split the work across BOTH pipes: .x on trans, .y as NR bit-hack + one
// Newton step on the full-rate main VALU. NR rel err ~0.1-0.2% one-sided
// -> output bias ~0.2 vs threshold 10.48 (R9 passed full-NR, absmax 4.0).
__device__ __forceinline__ v2f sqrt_hyb(v2f s) {
    v2f r;
    r.x = __builtin_amdgcn_sqrtf(s.x);                              // trans pipe
    float r0 = __uint_as_float(0x5F375A86u - (__float_as_uint(s.y) >> 1));
    float a  = s.y * r0;            // ~sqrt(s.y)
    float b  = a * r0;              // ~1
    r.y = a * (1.5f - 0.5f * b);    // Newton: sqrt * (1 +- ~0.002)   main VALU
    return r;
}

// Kernel 2: block = 32-entity tile x all 256 d, all 32 batches (R8 structure,
// best measured: 1352 blocks, direct stores, v4f interleaved LDS rows of 17
// float4 — verified ~0-conflict). Per-thread tile: 2 batch x 2 entity.
// ONLY change vs R8: sqrt_hyb instead of all-trans sqrt2.
__global__ __launch_bounds__(256, 6) void dist_kernel(const float* __restrict__ ent,
                                                      const float4* __restrict__ rot_v4,
                                                      float* __restrict__ out) {
    __shared__ v4f s_e[TE][DK / 2 + 1];   // 32 x 17 x 16 B = 8.7 KB
    __shared__ v4f s_r[NB][DK / 2 + 1];   // 32 x 17 x 16 B = 8.7 KB

    const int tid = threadIdx.x;
    const int eb  = blockIdx.x * TE;
    const int ep  = tid & 15;          // entities {ep, ep+16}
    const int bp  = tid >> 4;          // batches {2bp, 2bp+1}

    const int srow = tid >> 3;                 // 0..31
    const int c4   = tid & 7;                  // quad: d = dk + 4*c4
    const int er   = min(eb + srow, E_TOT - 1);
    const int rrow = tid >> 4;                 // 0..15 (and +16)
    const int rdp  = tid & 15;                 // dpair within chunk

    float4 p_re, p_im, p_r0, p_r1;

    auto load_chunk = [&](int c) {
        const int dk = c * DK;
        const float* b0 = &ent[(size_t)er * (2 * DIMH)];
        p_re = *reinterpret_cast<const float4*>(b0 + dk + 4 * c4);
        p_im = *reinterpret_cast<const float4*>(b0 + DIMH + dk + 4 * c4);
        p_r0 = rot_v4[rrow * (DIMH / 2) + c * (DK / 2) + rdp];
        p_r1 = rot_v4[(rrow + 16) * (DIMH / 2) + c * (DK / 2) + rdp];
    };

    v2f acc[2][2];   // [batch j][entity k]
    #pragma unroll
    for (int j = 0; j < 2; ++j)
        #pragma unroll
        for (int k = 0; k < 2; ++k) { acc[j][k].x = 0.f; acc[j][k].y = 0.f; }

    load_chunk(0);

    for (int c = 0; c < NC; ++c) {
        // ---- store prefetched regs to LDS (interleave ent re/im into v4f)
        {
            v4f lo, hi;
            lo.x = p_re.x; lo.y = p_re.y; lo.z = p_im.x; lo.w = p_im.y;
            hi.x = p_re.z; hi.y = p_re.w; hi.z = p_im.z; hi.w = p_im.w;
            s_e[srow][2 * c4]     = lo;
            s_e[srow][2 * c4 + 1] = hi;
            v4f r0, r1;
            r0.x = p_r0.x; r0.y = p_r0.y; r0.z = p_r0.z; r0.w = p_r0.w;
            r1.x = p_r1.x; r1.y = p_r1.y; r1.z = p_r1.z; r1.w = p_r1.w;
            s_r[rrow][rdp]      = r0;
            s_r[rrow + 16][rdp] = r1;
        }
        __syncthreads();

        // ---- issue next chunk's global loads (consumed after next barrier)
        if (c + 1 < NC) load_chunk(c + 1);

        #pragma unroll 4
        for (int p = 0; p < DK / 2; ++p) {
            v4f r0 = s_r[2 * bp][p];
            v4f r1 = s_r[2 * bp + 1][p];
            v4f e0 = s_e[ep][p];
            v4f e1 = s_e[ep + 16][p];

            {   v2f a = r0.xy - e0.xy, b = r0.zw - e0.zw;
                acc[0][0] += sqrt_hyb(a * a + b * b); }
            {   v2f a = r0.xy - e1.xy, b = r0.zw - e1.zw;
                acc[0][1] += sqrt_hyb(a * a + b * b); }
            {   v2f a = r1.xy - e0.xy, b = r1.zw - e0.zw;
                acc[1][0] += sqrt_hyb(a * a + b * b); }
            {   v2f a = r1.xy - e1.xy, b = r1.zw - e1.zw;
                acc[1][1] += sqrt_hyb(a * a + b * b); }
        }
        __syncthreads();
    }

    #pragma unroll
    for (int k = 0; k < 2; ++k) {
        int e = eb + ep + 16 * k;
        if (e < E_TOT) {
            #pragma unroll
            for (int j = 0; j < 2; ++j)
                out[(size_t)(2 * bp + j) * E_TOT + e] = 6.0f - (acc[j][k].x + acc[j][k].y);
        }
    }
}

extern "C" void kernel_launch(void* const* d_in, const int* in_sizes, int n_in,
                              void* d_out, int out_size, void* d_ws, size_t ws_size,
                              hipStream_t stream) {
    const float* head = (const float*)d_in[0];   // (32, 512)
    const float* rel  = (const float*)d_in[1];   // (32, 256)
    const float* ent  = (const float*)d_in[2];   // (43234, 512)
    float4* rot_v4 = (float4*)d_ws;              // 32 * 128 * 16 B = 64 KB

    rot_kernel<<<(NB * DIMH / 2) / 256, 256, 0, stream>>>(head, rel, rot_v4);

    int etiles = (E_TOT + TE - 1) / TE;          // 1352
    dist_kernel<<<etiles, 256, 0, stream>>>(ent, rot_v4, (float*)d_out);
}